// Round 9
// baseline (546.582 us; speedup 1.0000x reference)
//
#include <hip/hip_runtime.h>
#include <hip/hip_cooperative_groups.h>

namespace cg = cooperative_groups;

// Varlen non-causal attention, qkv-packed (T,3,H,D) fp32 in/out.
// Single cooperative kernel, 3 phases separated by grid.sync():
//  ph1: fp32 qkv -> bf16 Kb[h][t][d], Vtb[h][d][t]
//  ph2: bf16 MFMA flash attention (R4 structure: global_load_lds(16B) staging,
//       XOR-swizzled LDS, 2 barriers/chunk, split-K x2, Q converted in-kernel)
//  ph3: split-K combine
// Fallback to 3 separate kernels if cooperative launch is rejected.

#define HEADS 8
#define DH 64
#define TQ 64
#define TK 64
#define PSTR 72
#define NSPLIT 2
#define NEG_BIG -1e30f
#define L2E 1.44269504088896340736f

using f32x4 = __attribute__((ext_vector_type(4))) float;
using s16x8 = __attribute__((ext_vector_type(8))) short;

__device__ inline unsigned short bf16b(float x) {
    union { float f; unsigned u; } c; c.f = x;
    unsigned r = c.u + 0x7fffu + ((c.u >> 16) & 1u);   // RNE
    return (unsigned short)(r >> 16);
}

#if __has_builtin(__builtin_amdgcn_cvt_pk_bf16_f32)
__device__ inline unsigned pk2(float a, float b) {
    auto v = __builtin_amdgcn_cvt_pk_bf16_f32(a, b);
    unsigned u; __builtin_memcpy(&u, &v, 4); return u;
}
#else
__device__ inline unsigned pk2(float a, float b) {
    return (unsigned)bf16b(a) | ((unsigned)bf16b(b) << 16);
}
#endif

// ---------------- phase 1 body: convert + re-layout K,V ----------------
__device__ __forceinline__ void dev_prep(const float* __restrict__ qkv,
                                         unsigned short* __restrict__ Kb,
                                         unsigned short* __restrict__ Vtb,
                                         int T, int m, int h, int t0, int tid,
                                         unsigned short (*Lt)[PSTR]) {
    const int d8 = tid & 7, tr = tid >> 3;   // tr 0..31
    #pragma unroll
    for (int i = 0; i < 2; ++i) {
        int t = t0 + i * 32 + tr;
        int tc = t < T ? t : T - 1;
        const float* src = qkv + ((size_t)tc * 3 + m) * (HEADS * DH) + h * DH + d8 * 8;
        float4 a = *(const float4*)src;
        float4 b = *(const float4*)(src + 4);
        unsigned p0 = pk2(a.x, a.y), p1 = pk2(a.z, a.w);
        unsigned p2 = pk2(b.x, b.y), p3 = pk2(b.z, b.w);
        if (m == 2) {
            *(uint2*)&Lt[i * 32 + tr][d8 * 8]     = make_uint2(p0, p1);
            *(uint2*)&Lt[i * 32 + tr][d8 * 8 + 4] = make_uint2(p2, p3);
        } else if (t < T) {
            *(uint4*)(Kb + ((size_t)h * T + t) * DH + d8 * 8) = make_uint4(p0, p1, p2, p3);
        }
    }
    if (m == 2) {
        __syncthreads();
        const int d = tid >> 2, tg = tid & 3;
        #pragma unroll
        for (int p = 0; p < 2; ++p) {
            int G = tg + 4 * p;
            int td = t0 + G * 8;
            unsigned u[4];
            #pragma unroll
            for (int jj = 0; jj < 4; ++jj)
                u[jj] = (unsigned)Lt[G * 8 + 2 * jj][d] |
                        ((unsigned)Lt[G * 8 + 2 * jj + 1][d] << 16);
            if (td < T)
                *(uint4*)(Vtb + ((size_t)h * DH + d) * T + td) =
                    make_uint4(u[0], u[1], u[2], u[3]);
        }
    }
}

// ---------------- phase 2 body: flash attention (R4 structure) ----------------
__device__ __forceinline__ void dev_main(const float* __restrict__ qkv,
                                         const unsigned short* __restrict__ Kb,
                                         const unsigned short* __restrict__ Vtb,
                                         const int* __restrict__ cu, int n_cu, int T,
                                         float* __restrict__ Opart, float* __restrict__ Mp,
                                         float* __restrict__ Lp,
                                         int bx, int h, int split, int tid,
                                         unsigned short* Ksh, unsigned short* Vsh,
                                         unsigned short (*Psh)[PSTR]) {
    const int t0 = bx * TQ;
    const int w = tid >> 6, lane = tid & 63, n15 = lane & 15, quad = lane >> 4;

    // ---- segment bounds ----
    int trow = t0 + w * 16 + n15; if (trow > T - 1) trow = T - 1;
    int lo, hi;
    { int s = 0; for (int j = 1; j < n_cu - 1; ++j) if (cu[j] <= trow) s = j;
      lo = cu[s]; hi = cu[s + 1]; }
    int kb_, ke;
    { int s = 0; for (int j = 1; j < n_cu - 1; ++j) if (cu[j] <= t0) s = j;
      kb_ = cu[s];
      int tl = t0 + TQ - 1; if (tl > T - 1) tl = T - 1;
      s = 0; for (int j = 1; j < n_cu - 1; ++j) if (cu[j] <= tl) s = j;
      ke = cu[s + 1]; }

    // ---- Q fragments: load fp32, fold 0.125, pack bf16 ----
    s16x8 qfrag[2];
    {
        int tc = t0 + w * 16 + n15; if (tc > T - 1) tc = T - 1;
        const float* qp = qkv + (size_t)tc * 3 * (HEADS * DH) + h * DH + quad * 8;
        #pragma unroll
        for (int kh = 0; kh < 2; ++kh) {
            float4 a = *(const float4*)(qp + kh * 32);
            float4 b = *(const float4*)(qp + kh * 32 + 4);
            unsigned u0 = pk2(a.x * 0.125f, a.y * 0.125f);
            unsigned u1 = pk2(a.z * 0.125f, a.w * 0.125f);
            unsigned u2 = pk2(b.x * 0.125f, b.y * 0.125f);
            unsigned u3 = pk2(b.z * 0.125f, b.w * 0.125f);
            uint4 uu = make_uint4(u0, u1, u2, u3);
            __builtin_memcpy(&qfrag[kh], &uu, 16);
        }
    }

    // ---- staging lane constants (XOR-swizzled LDS granules) ----
    const unsigned short* kb_h = Kb + (size_t)h * T * DH;
    const unsigned short* vt_h = Vtb + (size_t)h * DH * T;
    int krow_rel[2], vkey_off[2], ldst[2];
    const unsigned short* kbase[2];
    const unsigned short* vbase[2];
    #pragma unroll
    for (int i = 0; i < 2; ++i) {
        int gg = i * 64 + lane;
        int rr = gg >> 3;
        int gc = gg & 7;
        int row = w * 16 + rr;            // 0..63
        int gcol = gc ^ (row & 7);
        krow_rel[i] = row;
        kbase[i] = kb_h + gcol * 8;
        vbase[i] = vt_h + (size_t)row * T;
        vkey_off[i] = gcol * 8;
        ldst[i] = (w * 128 + i * 64) * 8;
    }
    int off16[2];
    #pragma unroll
    for (int kh = 0; kh < 2; ++kh)
        off16[kh] = n15 * 128 + (((kh * 4 + quad) ^ (n15 & 7)) * 16);

    f32x4 oacc[4];
    #pragma unroll
    for (int i = 0; i < 4; ++i) oacc[i] = (f32x4){0.f, 0.f, 0.f, 0.f};
    float m_ = NEG_BIG, l_ = 0.f;

    const int step = NSPLIT * TK;
    const int c0_start = (kb_ / TK) * TK + split * TK;

    for (int c0 = c0_start; c0 < ke; c0 += step) {
        // ---- stage K + Vt via async 16B DMA ----
        #pragma unroll
        for (int i = 0; i < 2; ++i) {
            int rk = c0 + krow_rel[i]; if (rk > T - 1) rk = T - 1;
            __builtin_amdgcn_global_load_lds(
                (const __attribute__((address_space(1))) void*)(kbase[i] + ((size_t)rk << 6)),
                (__attribute__((address_space(3))) void*)&Ksh[ldst[i]], 16, 0, 0);
            int kv = c0 + vkey_off[i]; if (kv > T - 8) kv = T - 8;
            __builtin_amdgcn_global_load_lds(
                (const __attribute__((address_space(1))) void*)(vbase[i] + kv),
                (__attribute__((address_space(3))) void*)&Vsh[ldst[i]], 16, 0, 0);
        }
        __syncthreads();

        // ---- S^T = K·Q^T ----
        const char* Kc = (const char*)Ksh;
        f32x4 sacc[4];
        #pragma unroll
        for (int nt = 0; nt < 4; ++nt) {
            s16x8 k0 = *(const s16x8*)(Kc + nt * 2048 + off16[0]);
            s16x8 k1 = *(const s16x8*)(Kc + nt * 2048 + off16[1]);
            f32x4 z = (f32x4){0.f, 0.f, 0.f, 0.f};
            z = __builtin_amdgcn_mfma_f32_16x16x32_bf16(k0, qfrag[0], z, 0, 0, 0);
            z = __builtin_amdgcn_mfma_f32_16x16x32_bf16(k1, qfrag[1], z, 0, 0, 0);
            sacc[nt] = z;
        }

        // ---- mask (boundary chunks only) ----
        if (!(c0 >= lo && c0 + TK <= hi)) {
            #pragma unroll
            for (int nt = 0; nt < 4; ++nt)
                #pragma unroll
                for (int reg = 0; reg < 4; ++reg) {
                    int key = c0 + nt * 16 + quad * 4 + reg;
                    bool valid = (key >= lo) && (key < hi);
                    sacc[nt][reg] = valid ? sacc[nt][reg] : NEG_BIG;
                }
        }

        // ---- online softmax ----
        float rm = NEG_BIG;
        #pragma unroll
        for (int nt = 0; nt < 4; ++nt)
            #pragma unroll
            for (int reg = 0; reg < 4; ++reg) rm = fmaxf(rm, sacc[nt][reg]);
        rm = fmaxf(rm, __shfl_xor(rm, 16));
        rm = fmaxf(rm, __shfl_xor(rm, 32));
        float mn = fmaxf(m_, rm);
        float alpha = exp2f((m_ - mn) * L2E);
        float mnl = mn * L2E;
        float rs = 0.f;
        #pragma unroll
        for (int nt = 0; nt < 4; ++nt) {
            float p0 = exp2f(fmaf(sacc[nt][0], L2E, -mnl));
            float p1 = exp2f(fmaf(sacc[nt][1], L2E, -mnl));
            float p2 = exp2f(fmaf(sacc[nt][2], L2E, -mnl));
            float p3 = exp2f(fmaf(sacc[nt][3], L2E, -mnl));
            rs += (p0 + p1) + (p2 + p3);
            *(uint2*)&Psh[w * 16 + n15][nt * 16 + quad * 4] =
                make_uint2(pk2(p0, p1), pk2(p2, p3));
        }
        rs += __shfl_xor(rs, 16);
        rs += __shfl_xor(rs, 32);
        l_ = fmaf(l_, alpha, rs);
        m_ = mn;
        #pragma unroll
        for (int reg = 0; reg < 4; ++reg) {
            float ar = __shfl(alpha, quad * 4 + reg);
            oacc[0][reg] *= ar; oacc[1][reg] *= ar;
            oacc[2][reg] *= ar; oacc[3][reg] *= ar;
        }

        // ---- PV ----
        s16x8 afr[2];
        afr[0] = *(const s16x8*)&Psh[w * 16 + n15][quad * 8];
        afr[1] = *(const s16x8*)&Psh[w * 16 + n15][32 + quad * 8];
        const char* Vc = (const char*)Vsh;
        #pragma unroll
        for (int nt = 0; nt < 4; ++nt) {
            s16x8 v0 = *(const s16x8*)(Vc + nt * 2048 + off16[0]);
            s16x8 v1 = *(const s16x8*)(Vc + nt * 2048 + off16[1]);
            oacc[nt] = __builtin_amdgcn_mfma_f32_16x16x32_bf16(afr[0], v0, oacc[nt], 0, 0, 0);
            oacc[nt] = __builtin_amdgcn_mfma_f32_16x16x32_bf16(afr[1], v1, oacc[nt], 0, 0, 0);
        }
        __syncthreads();
    }

    // ---- epilogue: split-K partials ----
    #pragma unroll
    for (int reg = 0; reg < 4; ++reg) {
        int t = t0 + w * 16 + quad * 4 + reg;
        if (t < T) {
            size_t base = (((size_t)split * T + t) * HEADS + h) * DH;
            #pragma unroll
            for (int nt = 0; nt < 4; ++nt)
                Opart[base + nt * 16 + n15] = oacc[nt][reg];
        }
    }
    int tq = t0 + w * 16 + n15;
    if (quad == 0 && tq < T) {
        size_t mi = ((size_t)split * T + tq) * HEADS + h;
        Mp[mi] = m_; Lp[mi] = l_;
    }
}

// ---------------- phase 3 body: combine one float4 ----------------
__device__ __forceinline__ void dev_combine_one(const float* __restrict__ Opart,
                                                const float* __restrict__ Mp,
                                                const float* __restrict__ Lp,
                                                float* __restrict__ out, int T, int i4) {
    int th = i4 / (DH / 4);
    int d4 = i4 - th * (DH / 4);
    size_t stride = (size_t)T * HEADS * DH;
    int mlstride = T * HEADS;
    float m[NSPLIT], l[NSPLIT];
    float M = NEG_BIG;
    #pragma unroll
    for (int s = 0; s < NSPLIT; ++s) {
        m[s] = Mp[(size_t)s * mlstride + th];
        l[s] = Lp[(size_t)s * mlstride + th];
        M = fmaxf(M, m[s]);
    }
    float L = 0.f, wgt[NSPLIT];
    #pragma unroll
    for (int s = 0; s < NSPLIT; ++s) {
        wgt[s] = exp2f((m[s] - M) * L2E);
        L = fmaf(l[s], wgt[s], L);
    }
    float inv = 1.f / fmaxf(L, 1e-30f);
    size_t off = (size_t)th * DH + 4 * d4;
    float4 o = make_float4(0.f, 0.f, 0.f, 0.f);
    #pragma unroll
    for (int s = 0; s < NSPLIT; ++s) {
        float4 a = *(const float4*)&Opart[(size_t)s * stride + off];
        float ws = wgt[s];
        o.x = fmaf(a.x, ws, o.x); o.y = fmaf(a.y, ws, o.y);
        o.z = fmaf(a.z, ws, o.z); o.w = fmaf(a.w, ws, o.w);
    }
    o.x *= inv; o.y *= inv; o.z *= inv; o.w *= inv;
    *(float4*)&out[off] = o;
}

// ---------------- fused cooperative kernel ----------------
__global__ __launch_bounds__(256, 4)
void fa_fused(const float* __restrict__ qkv, const int* __restrict__ cu,
              int n_cu, int T, float* __restrict__ out,
              float* __restrict__ Opart, float* __restrict__ Mp, float* __restrict__ Lp,
              unsigned short* __restrict__ Kb, unsigned short* __restrict__ Vtb) {
    __shared__ unsigned short Lt[64][PSTR];
    __shared__ unsigned short Ksh[TK * DH];
    __shared__ unsigned short Vsh[TK * DH];
    __shared__ unsigned short Psh[TQ][PSTR];

    const int tid = threadIdx.x;
    const int bx = blockIdx.x, by = blockIdx.y, bz = blockIdx.z;
    cg::grid_group grid = cg::this_grid();

    // phase 1: blocks (bx=tile, by=head, bz: 0->K, 1->V)
    dev_prep(qkv, Kb, Vtb, T, bz + 1, by, bx * 64, tid, Lt);

    __threadfence();
    grid.sync();

    // phase 2: bx=q-tile, by=head, bz=split
    dev_main(qkv, Kb, Vtb, cu, n_cu, T, Opart, Mp, Lp, bx, by, bz, tid, Ksh, Vsh, Psh);

    __threadfence();
    grid.sync();

    // phase 3: combine, grid-stride
    int total4 = T * HEADS * (DH / 4);
    int nthr = (int)(gridDim.x * gridDim.y * gridDim.z * blockDim.x);
    int gid = (int)(((bz * gridDim.y + by) * gridDim.x + bx) * blockDim.x) + tid;
    for (int i4 = gid; i4 < total4; i4 += nthr)
        dev_combine_one(Opart, Mp, Lp, out, T, i4);
}

// ---------------- fallback separate kernels ----------------
__global__ __launch_bounds__(256)
void prep_kernel(const float* __restrict__ qkv, unsigned short* __restrict__ Kb,
                 unsigned short* __restrict__ Vtb, int T) {
    __shared__ unsigned short Lt[64][PSTR];
    dev_prep(qkv, Kb, Vtb, T, blockIdx.z + 1, blockIdx.y, blockIdx.x * 64, threadIdx.x, Lt);
}

__global__ __launch_bounds__(256, 4)
void fa_main_kernel(const float* __restrict__ qkv, const unsigned short* __restrict__ Kb,
                    const unsigned short* __restrict__ Vtb, const int* __restrict__ cu,
                    int n_cu, int T, float* __restrict__ Opart,
                    float* __restrict__ Mp, float* __restrict__ Lp) {
    __shared__ unsigned short Ksh[TK * DH];
    __shared__ unsigned short Vsh[TK * DH];
    __shared__ unsigned short Psh[TQ][PSTR];
    dev_main(qkv, Kb, Vtb, cu, n_cu, T, Opart, Mp, Lp,
             blockIdx.x, blockIdx.y, blockIdx.z, threadIdx.x, Ksh, Vsh, Psh);
}

__global__ __launch_bounds__(256)
void fa_combine_kernel(const float* __restrict__ Opart, const float* __restrict__ Mp,
                       const float* __restrict__ Lp, float* __restrict__ out, int T) {
    int i4 = blockIdx.x * blockDim.x + threadIdx.x;
    if (i4 < T * HEADS * (DH / 4))
        dev_combine_one(Opart, Mp, Lp, out, T, i4);
}

extern "C" void kernel_launch(void* const* d_in, const int* in_sizes, int n_in,
                              void* d_out, int out_size, void* d_ws, size_t ws_size,
                              hipStream_t stream) {
    const float* qkv = (const float*)d_in[0];
    const int* cu    = (const int*)d_in[1];
    int n_cu         = in_sizes[1];
    int T            = in_sizes[0] / (3 * HEADS * DH);
    float* out       = (float*)d_out;

    size_t elems = (size_t)T * HEADS * DH;

    float* Opart = (float*)d_ws;                                  // NSPLIT*elems f32
    float* Mpp   = Opart + (size_t)NSPLIT * elems;                // NSPLIT*T*H f32
    float* Lpp   = Mpp + (size_t)NSPLIT * T * HEADS;
    unsigned short* Kb  = (unsigned short*)(Lpp + (size_t)NSPLIT * T * HEADS);
    unsigned short* Vtb = Kb + elems;

    int tiles = (T + TQ - 1) / TQ;
    dim3 grid(tiles, HEADS, NSPLIT);
    int total4 = T * HEADS * (DH / 4);

    void* kargs[] = {(void*)&qkv, (void*)&cu, (void*)&n_cu, (void*)&T, (void*)&out,
                     (void*)&Opart, (void*)&Mpp, (void*)&Lpp, (void*)&Kb, (void*)&Vtb};
    hipError_t err = hipLaunchCooperativeKernel(reinterpret_cast<void*>(fa_fused),
                                                grid, dim3(256, 1, 1), kargs, 0, stream);
    if (err != hipSuccess) {
        // fallback: 3-kernel pipeline (R4 structure)
        prep_kernel<<<dim3(tiles, HEADS, 2), 256, 0, stream>>>(qkv, Kb, Vtb, T);
        fa_main_kernel<<<grid, 256, 0, stream>>>(qkv, Kb, Vtb, cu, n_cu, T, Opart, Mpp, Lpp);
        fa_combine_kernel<<<(total4 + 255) / 256, 256, 0, stream>>>(Opart, Mpp, Lpp, out, T);
    }
}